// Round 5
// baseline (587.819 us; speedup 1.0000x reference)
//
#include <hip/hip_runtime.h>
#include <cstdint>
#include <cmath>

using u16 = unsigned short;
typedef __attribute__((ext_vector_type(4))) short s16x4;
typedef __attribute__((ext_vector_type(8))) short s16x8;
typedef __attribute__((ext_vector_type(8))) __bf16 bf16x8;
typedef __attribute__((ext_vector_type(4))) float f32x4;

static __device__ __forceinline__ float b2f(u16 u) {
    unsigned int x = ((unsigned int)u) << 16;
    float f; __builtin_memcpy(&f, &x, 4); return f;
}
static __device__ __forceinline__ u16 f2b(float f) {
    unsigned int x; __builtin_memcpy(&x, &f, 4);
    x += 0x7FFFu + ((x >> 16) & 1u);           // round-to-nearest-even
    return (u16)(x >> 16);
}
static __device__ __forceinline__ bf16x8 as_bf(s16x8 s) {
    return __builtin_bit_cast(bf16x8, s);
}

#define NEGBIG (-1e30f)

// ------------- GEMM: C[M][N] = A[M][K] @ B[K][N]  (fp32 or bf16 A; fp32 B; bf16/fp32 C) -----
// 128x128 tile, BK=64, 4 waves (2x2), each wave 64x64 via 4x4 16x16x32 MFMA frags.
// A staged row-major (bf16-converted); B staged with in-LDS transpose+cvt (Bs[n][k]).
template <typename TA, typename TC>
__global__ __launch_bounds__(256) void k_gemm(const TA* __restrict__ A,
                                              const float* __restrict__ B,
                                              TC* __restrict__ C,
                                              int M, int N, int K) {
    __shared__ u16 As[128][72];
    __shared__ u16 Bs[128][72];                  // [n][k], padded
    int bm = blockIdx.y * 128, bn = blockIdx.x * 128;
    int tid = threadIdx.x, wid = tid >> 6, lane = tid & 63;
    int l15 = lane & 15, g = lane >> 4;
    int wr = (wid >> 1) * 64, wc = (wid & 1) * 64;
    f32x4 acc[4][4];
    for (int i = 0; i < 4; ++i) for (int j = 0; j < 4; ++j) acc[i][j] = f32x4{0.f,0.f,0.f,0.f};

    int asr = tid >> 1;                          // A staging: 128 rows x 2 threads
    int bkr = tid >> 2, bc = (tid & 3) * 32;     // B staging: 64 k-rows x 4 threads, 32 cols each

    for (int kb = 0; kb < K; kb += 64) {
        __syncthreads();
        if constexpr (sizeof(TA) == 4) {         // fp32 A: float4 loads + cvt
            int asc = (tid & 1) * 32;
            const float* pa = (const float*)A + (size_t)(bm + asr) * K + kb + asc;
            for (int it = 0; it < 8; ++it) {
                f32x4 v = *(const f32x4*)(pa + it * 4);
                s16x4 b;
                for (int j = 0; j < 4; ++j) b[j] = (short)f2b(v[j]);
                *(s16x4*)&As[asr][asc + it * 4] = b;
            }
        } else {                                 // bf16 A: s16x8 loads
            int asc = (tid & 1) * 8;
            const u16* pa = (const u16*)A + (size_t)(bm + asr) * K + kb + asc;
            for (int it = 0; it < 4; ++it)
                *(s16x8*)&As[asr][asc + it * 16] = *(const s16x8*)(pa + it * 16);
        }
        {   // B: fp32 [K][N] -> Bs[n][k] bf16 (transpose in LDS)
            const float* pb = B + (size_t)(kb + bkr) * N + bn + bc;
            for (int it = 0; it < 8; ++it) {
                f32x4 v = *(const f32x4*)(pb + it * 4);
                for (int j = 0; j < 4; ++j) Bs[bc + it * 4 + j][bkr] = f2b(v[j]);
            }
        }
        __syncthreads();
        for (int kk = 0; kk < 64; kk += 32) {
            bf16x8 af[4], bfr[4];
            for (int mi = 0; mi < 4; ++mi)
                af[mi] = as_bf(*(const s16x8*)&As[wr + mi * 16 + l15][kk + g * 8]);
            for (int ni = 0; ni < 4; ++ni)
                bfr[ni] = as_bf(*(const s16x8*)&Bs[wc + ni * 16 + l15][kk + g * 8]);
            for (int mi = 0; mi < 4; ++mi)
                for (int ni = 0; ni < 4; ++ni)
                    acc[mi][ni] = __builtin_amdgcn_mfma_f32_16x16x32_bf16(af[mi], bfr[ni], acc[mi][ni], 0, 0, 0);
        }
    }
    for (int mi = 0; mi < 4; ++mi)
        for (int ni = 0; ni < 4; ++ni) {
            int row = bm + wr + mi * 16 + g * 4;
            int col = bn + wc + ni * 16 + l15;
            for (int rr = 0; rr < 4; ++rr) {
                if constexpr (sizeof(TC) == 4)
                    ((float*)C)[(size_t)(row + rr) * N + col] = acc[mi][ni][rr];
                else
                    ((u16*)C)[(size_t)(row + rr) * N + col] = f2b(acc[mi][ni][rr]);
            }
        }
}

// ---------------- RMSNorm + RoPE, IN PLACE (bf16 buffers, fp32 norm weights) ----------------
// qg: [2048][4096] (head h: q at h*256+[0,128), gate at h*256+128+[0,128)) - q slots rewritten
// kp: [2048][512]  (head h at h*128) - rewritten
__global__ __launch_bounds__(256) void k_normrope(u16* __restrict__ qg,
                                                  u16* __restrict__ kp,
                                                  const float* __restrict__ qw,
                                                  const float* __restrict__ kw,
                                                  const int* __restrict__ pos) {
    int t = blockIdx.x;
    int tid = threadIdx.x, w = tid >> 6, l = tid & 63;
    float fp = (float)pos[t];
    int j = l & 31;
    // inv_freq = 10000^(-j/32)
    float invf = expf(-(float)j * (9.210340371976184f / 32.f));
    float sv, cv;
    sincosf(fp * invf, &sv, &cv);
    for (int task = w; task < 20; task += 4) {
        u16* p; const float* ww;
        if (task < 16) { p = qg + (size_t)t * 4096 + task * 256; ww = qw; }
        else           { p = kp + (size_t)t * 512 + (task - 16) * 128; ww = kw; }
        float v0 = b2f(p[l]), v1 = b2f(p[l + 64]);
        float ss = v0 * v0 + v1 * v1;
        for (int m = 32; m; m >>= 1) ss += __shfl_xor(ss, m);
        float rn = rsqrtf(ss * (1.f / 128.f) + 1e-6f);
        float q0 = v0 * rn * (1.f + ww[l]);
        float q1 = v1 * rn * (1.f + ww[l + 64]);
        float other = __shfl_xor(q0, 32);
        float ro = (l < 32) ? (q0 * cv - other * sv) : (q0 * cv + other * sv);
        p[l] = f2b(ro);           // dims 0..63 (rotary)
        p[l + 64] = f2b(q1);      // dims 64..127 (pass-through)
    }
}

// ---------------- causal GQA flash attention + sigmoid gate ----------------
// qg [2048][4096] (normed q + raw gate, bf16), kp [2048][512], vp [2048][512]
// yg [2048][2048] bf16 (row t, col h*128+d), gated.
__global__ __launch_bounds__(256) void k_attn(const u16* __restrict__ qg,
                                              const u16* __restrict__ kp,
                                              const u16* __restrict__ vp,
                                              u16* __restrict__ yg) {
    __shared__ u16 Kl[32 * 128];       // XOR-swizzled [key][d]
    __shared__ u16 Vt[128][40];        // transposed [d][key], padded
    __shared__ u16 Pl[4][16][40];      // per-wave P tile [qrow][key]
    int head = blockIdx.y, kvh = head >> 2;
    int qb0 = blockIdx.x * 64;
    int tid = threadIdx.x, wid = tid >> 6, lane = tid & 63;
    int l15 = lane & 15, g = lane >> 4;

    bf16x8 qf[4];
    {
        const u16* qp = qg + (size_t)(qb0 + wid * 16 + l15) * 4096 + head * 256 + g * 8;
        for (int c = 0; c < 4; ++c) qf[c] = as_bf(*(const s16x8*)(qp + c * 32));
    }
    f32x4 oacc[8];
    for (int nb = 0; nb < 8; ++nb) oacc[nb] = f32x4{0.f,0.f,0.f,0.f};
    float mrow[4] = {NEGBIG, NEGBIG, NEGBIG, NEGBIG};
    float lsum[4] = {0.f, 0.f, 0.f, 0.f};

    int sr = tid >> 3, sc0 = (tid & 7) * 16;
    int nkt = qb0 / 32 + 2;
    for (int kt = 0; kt < nkt; ++kt) {
        int k0 = kt * 32;
        __syncthreads();
        {   // stage K (swizzled) + V (transposed)
            const u16* ks = kp + (size_t)(k0 + sr) * 512 + kvh * 128 + sc0;
            char* kd = (char*)Kl + sr * 256;
            int sw = (sr & 7) << 4;
            *(s16x8*)(kd + ((sc0 * 2) ^ sw)) = *(const s16x8*)ks;
            *(s16x8*)(kd + ((sc0 * 2 + 16) ^ sw)) = *(const s16x8*)(ks + 8);
            const u16* vs = vp + (size_t)(k0 + sr) * 512 + kvh * 128 + sc0;
            for (int jj = 0; jj < 16; ++jj) Vt[sc0 + jj][sr] = vs[jj];
        }
        __syncthreads();

        f32x4 sc[2];
        sc[0] = f32x4{0.f,0.f,0.f,0.f}; sc[1] = f32x4{0.f,0.f,0.f,0.f};
        for (int h2 = 0; h2 < 2; ++h2) {
            int krow = h2 * 16 + l15;
            const char* kb_ = (const char*)Kl + krow * 256;
            int sw = (krow & 7) << 4;
            for (int c = 0; c < 4; ++c) {
                bf16x8 kf = as_bf(*(const s16x8*)(kb_ + ((c * 64 + g * 16) ^ sw)));
                sc[h2] = __builtin_amdgcn_mfma_f32_16x16x32_bf16(qf[c], kf, sc[h2], 0, 0, 0);
            }
        }
        const float scale = 0.08838834764831845f;   // 1/sqrt(128), fp32
        for (int r = 0; r < 4; ++r) {
            int tq = qb0 + wid * 16 + g * 4 + r;
            float s0 = (k0 + l15 > tq) ? NEGBIG : sc[0][r] * scale;
            float s1 = (k0 + 16 + l15 > tq) ? NEGBIG : sc[1][r] * scale;
            float pm = fmaxf(s0, s1);
            pm = fmaxf(pm, __shfl_xor(pm, 1, 16));
            pm = fmaxf(pm, __shfl_xor(pm, 2, 16));
            pm = fmaxf(pm, __shfl_xor(pm, 4, 16));
            pm = fmaxf(pm, __shfl_xor(pm, 8, 16));
            float nm = fmaxf(mrow[r], pm);
            float f = expf(mrow[r] - nm);
            float p0 = expf(s0 - nm), p1 = expf(s1 - nm);
            float rs = p0 + p1;
            rs += __shfl_xor(rs, 1, 16); rs += __shfl_xor(rs, 2, 16);
            rs += __shfl_xor(rs, 4, 16); rs += __shfl_xor(rs, 8, 16);
            mrow[r] = nm;
            lsum[r] = lsum[r] * f + rs;
            for (int nb = 0; nb < 8; ++nb) oacc[nb][r] *= f;
            Pl[wid][g * 4 + r][l15] = f2b(p0);
            Pl[wid][g * 4 + r][16 + l15] = f2b(p1);
        }
        bf16x8 pa = as_bf(*(const s16x8*)&Pl[wid][l15][g * 8]);
        for (int nb = 0; nb < 8; ++nb) {
            bf16x8 vb = as_bf(*(const s16x8*)&Vt[nb * 16 + l15][g * 8]);
            oacc[nb] = __builtin_amdgcn_mfma_f32_16x16x32_bf16(pa, vb, oacc[nb], 0, 0, 0);
        }
    }
    // epilogue: normalize, gate with sigmoid, store
    for (int nb = 0; nb < 8; ++nb) {
        for (int r = 0; r < 4; ++r) {
            int row = qb0 + wid * 16 + g * 4 + r;
            int col = nb * 16 + l15;
            float y = oacc[nb][r] / lsum[r];
            float gt = b2f(qg[(size_t)row * 4096 + head * 256 + 128 + col]);
            float sg = 1.f / (1.f + expf(-gt));
            yg[(size_t)row * 2048 + head * 128 + col] = f2b(y * sg);
        }
    }
}

// ---------------- launch ----------------
extern "C" void kernel_launch(void* const* d_in, const int* in_sizes, int n_in,
                              void* d_out, int out_size, void* d_ws, size_t ws_size,
                              hipStream_t stream) {
    const float* x   = (const float*)d_in[0];
    const int*   pos = (const int*)d_in[1];
    const float* wq  = (const float*)d_in[2];
    const float* wk  = (const float*)d_in[3];
    const float* wv  = (const float*)d_in[4];
    const float* wo  = (const float*)d_in[5];
    const float* qnw = (const float*)d_in[6];
    const float* knw = (const float*)d_in[7];
    float* out = (float*)d_out;
    char* ws = (char*)d_ws;

    // workspace layout (28 MB total, all bf16 intermediates)
    u16* qgb = (u16*)(ws + 0);          // 2048 x 4096  (16 MB)
    u16* kpb = (u16*)(ws + 16777216);   // 2048 x 512   (2 MB)
    u16* vpb = (u16*)(ws + 18874368);   // 2048 x 512   (2 MB)
    u16* ygb = (u16*)(ws + 20971520);   // 2048 x 2048  (8 MB)

    k_gemm<float, u16><<<dim3(4096 / 128, 2048 / 128), 256, 0, stream>>>(x, wq, qgb, 2048, 4096, 2048);
    k_gemm<float, u16><<<dim3(512 / 128, 2048 / 128), 256, 0, stream>>>(x, wk, kpb, 2048, 512, 2048);
    k_gemm<float, u16><<<dim3(512 / 128, 2048 / 128), 256, 0, stream>>>(x, wv, vpb, 2048, 512, 2048);

    k_normrope<<<2048, 256, 0, stream>>>(qgb, kpb, qnw, knw, pos);

    k_attn<<<dim3(2048 / 64, 16), 256, 0, stream>>>(qgb, kpb, vpb, ygb);

    k_gemm<u16, float><<<dim3(2048 / 128, 2048 / 128), 256, 0, stream>>>(ygb, wo, out, 2048, 2048, 2048);
}

// Round 6
// 287.664 us; speedup vs baseline: 2.0434x; 2.0434x over previous
//
#include <hip/hip_runtime.h>
#include <cstdint>
#include <cmath>

using u16 = unsigned short;
typedef __attribute__((ext_vector_type(4))) short s16x4;
typedef __attribute__((ext_vector_type(8))) short s16x8;
typedef __attribute__((ext_vector_type(8))) __bf16 bf16x8;
typedef __attribute__((ext_vector_type(4))) float f32x4;

static __device__ __forceinline__ float b2f(u16 u) {
    unsigned int x = ((unsigned int)u) << 16;
    float f; __builtin_memcpy(&f, &x, 4); return f;
}
static __device__ __forceinline__ u16 f2b(float f) {
    unsigned int x; __builtin_memcpy(&x, &f, 4);
    x += 0x7FFFu + ((x >> 16) & 1u);           // round-to-nearest-even
    return (u16)(x >> 16);
}
static __device__ __forceinline__ bf16x8 as_bf(s16x8 s) {
    return __builtin_bit_cast(bf16x8, s);
}

#define NEGBIG (-1e30f)

// ---- async 16B/lane global->LDS (wave-uniform LDS base, per-lane global src) ----
static __device__ __forceinline__ void stage16(const u16* g, u16* lds_base, int lane) {
#if __has_builtin(__builtin_amdgcn_global_load_lds)
    __builtin_amdgcn_global_load_lds((const __attribute__((address_space(1))) void*)g,
                                     (__attribute__((address_space(3))) void*)lds_base,
                                     16, 0, 0);
#else
    *(s16x8*)(lds_base + (size_t)lane * 8) = *(const s16x8*)g;
#endif
}

// ---------------- weight transpose+cvt: in fp32 [K][N] -> out bf16 [N][K] ----------------
__global__ __launch_bounds__(256) void k_wtrans(const float* __restrict__ in,
                                                u16* __restrict__ out,
                                                int K, int N) {
    __shared__ u16 tile[64][72];
    int nb = blockIdx.x * 64, kb = blockIdx.y * 64;
    int tid = threadIdx.x;
    int kr = tid >> 2, c0 = (tid & 3) * 16;
#pragma unroll
    for (int i = 0; i < 4; ++i) {
        f32x4 v = *(const f32x4*)(in + (size_t)(kb + kr) * N + nb + c0 + i * 4);
        s16x4 b;
        for (int j = 0; j < 4; ++j) b[j] = (short)f2b(v[j]);
        *(s16x4*)&tile[kr][c0 + i * 4] = b;
    }
    __syncthreads();
    int nr = tid >> 2, k0 = (tid & 3) * 16;
    s16x8 v0, v1;
    for (int j = 0; j < 8; ++j) { v0[j] = (short)tile[k0 + j][nr]; v1[j] = (short)tile[k0 + 8 + j][nr]; }
    *(s16x8*)(out + (size_t)(nb + nr) * K + kb + k0) = v0;
    *(s16x8*)(out + (size_t)(nb + nr) * K + kb + k0 + 8) = v1;
}

// ---------------- x fp32 -> bf16 ----------------
__global__ __launch_bounds__(256) void k_xcvt(const float* __restrict__ in,
                                              u16* __restrict__ out, int n4) {
    int i = blockIdx.x * 256 + threadIdx.x;
    int stride = gridDim.x * 256;
    for (; i < n4; i += stride) {
        f32x4 v = ((const f32x4*)in)[i];
        s16x4 b;
        for (int j = 0; j < 4; ++j) b[j] = (short)f2b(v[j]);
        ((s16x4*)out)[i] = b;
    }
}

// ------------- GEMM: C[M][N] = A[M][K] @ Bt[N][K]^T  (bf16 in, fp32 acc) -------------
// 128x128 tile, BK=64, 4 waves (2x2), global_load_lds staging, linear LDS.
template <bool OUT_F32>
__global__ __launch_bounds__(256) void k_gemm_bt(const u16* __restrict__ A,
                                                 const u16* __restrict__ Bt,
                                                 void* __restrict__ Cv,
                                                 int M, int N, int K) {
    __shared__ u16 As[128 * 64];
    __shared__ u16 Bs[128 * 64];
    int bm = blockIdx.y * 128, bn = blockIdx.x * 128;
    int tid = threadIdx.x, wid = tid >> 6, lane = tid & 63;
    int l15 = lane & 15, g = lane >> 4;
    int wr = (wid >> 1) * 64, wc = (wid & 1) * 64;
    f32x4 acc[4][4];
    for (int i = 0; i < 4; ++i) for (int j = 0; j < 4; ++j) acc[i][j] = f32x4{0.f, 0.f, 0.f, 0.f};

    // staging: chunk c covers rows c*8..c*8+8 (64 u16 each); lane l -> row c*8+(l>>3), k (l&7)*8
    int srow = lane >> 3, skcol = (lane & 7) * 8;
    const u16* pa = A + (size_t)(bm + srow) * K + skcol;
    const u16* pb = Bt + (size_t)(bn + srow) * K + skcol;

    for (int kb = 0; kb < K; kb += 64) {
        __syncthreads();
#pragma unroll
        for (int it = 0; it < 4; ++it) {
            int c = it * 4 + wid;
            stage16(pa + (size_t)(c * 8) * K + kb, &As[c * 512], lane);
            stage16(pb + (size_t)(c * 8) * K + kb, &Bs[c * 512], lane);
        }
        __syncthreads();
#pragma unroll
        for (int kk = 0; kk < 64; kk += 32) {
            bf16x8 af[4], bfr[4];
            for (int mi = 0; mi < 4; ++mi)
                af[mi] = as_bf(*(const s16x8*)&As[(wr + mi * 16 + l15) * 64 + kk + g * 8]);
            for (int ni = 0; ni < 4; ++ni)
                bfr[ni] = as_bf(*(const s16x8*)&Bs[(wc + ni * 16 + l15) * 64 + kk + g * 8]);
            for (int mi = 0; mi < 4; ++mi)
                for (int ni = 0; ni < 4; ++ni)
                    acc[mi][ni] = __builtin_amdgcn_mfma_f32_16x16x32_bf16(af[mi], bfr[ni], acc[mi][ni], 0, 0, 0);
        }
    }
    for (int mi = 0; mi < 4; ++mi)
        for (int ni = 0; ni < 4; ++ni) {
            int row = bm + wr + mi * 16 + g * 4;
            int col = bn + wc + ni * 16 + l15;
            for (int rr = 0; rr < 4; ++rr) {
                if (OUT_F32)
                    ((float*)Cv)[(size_t)(row + rr) * N + col] = acc[mi][ni][rr];
                else
                    ((u16*)Cv)[(size_t)(row + rr) * N + col] = f2b(acc[mi][ni][rr]);
            }
        }
}

// ---------------- RMSNorm + RoPE, IN PLACE on fused qkv [2048][5120] ----------------
// q of head h at cols h*256..h*256+128 (gate at +128, untouched); k at 4096+h*128
__global__ __launch_bounds__(256) void k_normrope(u16* __restrict__ qkv,
                                                  const float* __restrict__ qw,
                                                  const float* __restrict__ kw,
                                                  const int* __restrict__ pos) {
    int t = blockIdx.x;
    int tid = threadIdx.x, w = tid >> 6, l = tid & 63;
    float fp = (float)pos[t];
    int j = l & 31;
    float invf = __expf(-(float)j * (9.210340371976184f / 32.f));   // 10000^(-j/32)
    float sv, cv;
    sincosf(fp * invf, &sv, &cv);
    for (int task = w; task < 20; task += 4) {
        u16* p; const float* ww;
        if (task < 16) { p = qkv + (size_t)t * 5120 + task * 256; ww = qw; }
        else           { p = qkv + (size_t)t * 5120 + 4096 + (task - 16) * 128; ww = kw; }
        float v0 = b2f(p[l]), v1 = b2f(p[l + 64]);
        float ss = v0 * v0 + v1 * v1;
        for (int m = 32; m; m >>= 1) ss += __shfl_xor(ss, m);
        float rn = rsqrtf(ss * (1.f / 128.f) + 1e-6f);
        float q0 = v0 * rn * (1.f + ww[l]);
        float q1 = v1 * rn * (1.f + ww[l + 64]);
        float other = __shfl_xor(q0, 32);
        float ro = (l < 32) ? (q0 * cv - other * sv) : (q0 * cv + other * sv);
        p[l] = f2b(ro);
        p[l + 64] = f2b(q1);
    }
}

// ---------------- V transpose: qkv v-cols -> vT[kvh][d 128][t 2048] ----------------
__global__ __launch_bounds__(256) void k_vtrans(const u16* __restrict__ qkv,
                                                u16* __restrict__ vT) {
    __shared__ u16 tile[64][136];
    int tb = blockIdx.x * 64, kvh = blockIdx.y;
    int tid = threadIdx.x;
    int tr = tid >> 2, c0 = (tid & 3) * 32;
    const u16* src = qkv + (size_t)(tb + tr) * 5120 + 4608 + kvh * 128 + c0;
#pragma unroll
    for (int i = 0; i < 4; ++i)
        *(s16x8*)&tile[tr][c0 + i * 8] = *(const s16x8*)(src + i * 8);
    __syncthreads();
    int d = tid >> 1, t0 = (tid & 1) * 32;
    u16* dst = vT + ((size_t)kvh * 128 + d) * 2048 + tb + t0;
#pragma unroll
    for (int i = 0; i < 4; ++i) {
        s16x8 v;
        for (int j = 0; j < 8; ++j) v[j] = (short)tile[t0 + i * 8 + j][d];
        *(s16x8*)(dst + i * 8) = v;
    }
}

// ---------------- causal GQA flash attention + sigmoid gate ----------------
// Pair-balanced: block p handles q-tiles p and 31-p (QBLK=64); KVBLK=64.
__global__ __launch_bounds__(256) void k_attn(const u16* __restrict__ qkv,
                                              const u16* __restrict__ vT,
                                              u16* __restrict__ yg) {
    __shared__ u16 Kl[64 * 128];       // XOR-swizzled rows of 256B
    __shared__ u16 Vt[128][72];        // [d][key], padded (2-way free)
    __shared__ u16 Pl[4][16][72];      // per-wave P tile [qrow][key]
    int head = blockIdx.y, kvh = head >> 2;
    int p = blockIdx.x;
    int tid = threadIdx.x, wid = tid >> 6, lane = tid & 63;
    int l15 = lane & 15, g = lane >> 4;

    for (int half = 0; half < 2; ++half) {
        int qt = half ? (31 - p) : p;
        int qb0 = qt * 64;
        bf16x8 qf[4];
        {
            const u16* qp = qkv + (size_t)(qb0 + wid * 16 + l15) * 5120 + head * 256 + g * 8;
            for (int c = 0; c < 4; ++c) qf[c] = as_bf(*(const s16x8*)(qp + c * 32));
        }
        f32x4 oacc[8];
        for (int nb = 0; nb < 8; ++nb) oacc[nb] = f32x4{0.f, 0.f, 0.f, 0.f};
        float mrow[4] = {NEGBIG, NEGBIG, NEGBIG, NEGBIG};
        float lsum[4] = {0.f, 0.f, 0.f, 0.f};

        int nkt = qt + 1;
        for (int kt = 0; kt < nkt; ++kt) {
            int k0 = kt * 64;
            __syncthreads();
            {   // stage K (swizzled rows) + Vt (from pre-transposed vT)
                int sr = tid >> 2, sc0 = (tid & 3) * 32;
                const u16* ks = qkv + (size_t)(k0 + sr) * 5120 + 4096 + kvh * 128 + sc0;
                char* kd = (char*)Kl + sr * 256;
                int sw = (sr & 7) << 4;
#pragma unroll
                for (int c = 0; c < 4; ++c)
                    *(s16x8*)(kd + ((2 * (sc0 + 8 * c)) ^ sw)) = *(const s16x8*)(ks + 8 * c);
                int vr = tid >> 1, vc0 = (tid & 1) * 32;
                const u16* vs = vT + ((size_t)kvh * 128 + vr) * 2048 + k0 + vc0;
#pragma unroll
                for (int c = 0; c < 4; ++c)
                    *(s16x8*)&Vt[vr][vc0 + 8 * c] = *(const s16x8*)(vs + 8 * c);
            }
            __syncthreads();

            f32x4 sc4[4];
            for (int h2 = 0; h2 < 4; ++h2) sc4[h2] = f32x4{0.f, 0.f, 0.f, 0.f};
            for (int h2 = 0; h2 < 4; ++h2) {
                int krow = h2 * 16 + l15;
                const char* kb_ = (const char*)Kl + krow * 256;
                int sw = (krow & 7) << 4;
                for (int c = 0; c < 4; ++c) {
                    bf16x8 kf = as_bf(*(const s16x8*)(kb_ + ((c * 64 + g * 16) ^ sw)));
                    sc4[h2] = __builtin_amdgcn_mfma_f32_16x16x32_bf16(qf[c], kf, sc4[h2], 0, 0, 0);
                }
            }
            const float scale = 0.08838834764831845f;   // 1/sqrt(128)
            for (int r = 0; r < 4; ++r) {
                int tq = qb0 + wid * 16 + g * 4 + r;
                float s[4];
                float pm = NEGBIG;
                for (int h2 = 0; h2 < 4; ++h2) {
                    s[h2] = (k0 + h2 * 16 + l15 > tq) ? NEGBIG : sc4[h2][r] * scale;
                    pm = fmaxf(pm, s[h2]);
                }
                pm = fmaxf(pm, __shfl_xor(pm, 1, 16));
                pm = fmaxf(pm, __shfl_xor(pm, 2, 16));
                pm = fmaxf(pm, __shfl_xor(pm, 4, 16));
                pm = fmaxf(pm, __shfl_xor(pm, 8, 16));
                float nm = fmaxf(mrow[r], pm);
                float f = __expf(mrow[r] - nm);
                float rs = 0.f;
                for (int h2 = 0; h2 < 4; ++h2) {
                    float pv = __expf(s[h2] - nm);
                    rs += pv;
                    Pl[wid][g * 4 + r][h2 * 16 + l15] = f2b(pv);
                }
                rs += __shfl_xor(rs, 1, 16); rs += __shfl_xor(rs, 2, 16);
                rs += __shfl_xor(rs, 4, 16); rs += __shfl_xor(rs, 8, 16);
                mrow[r] = nm;
                lsum[r] = lsum[r] * f + rs;
                for (int nb = 0; nb < 8; ++nb) oacc[nb][r] *= f;
            }
            for (int kc = 0; kc < 2; ++kc) {
                bf16x8 pa = as_bf(*(const s16x8*)&Pl[wid][l15][kc * 32 + g * 8]);
                for (int nb = 0; nb < 8; ++nb) {
                    bf16x8 vb = as_bf(*(const s16x8*)&Vt[nb * 16 + l15][kc * 32 + g * 8]);
                    oacc[nb] = __builtin_amdgcn_mfma_f32_16x16x32_bf16(pa, vb, oacc[nb], 0, 0, 0);
                }
            }
        }
        // epilogue: normalize, gate with sigmoid, store
        for (int nb = 0; nb < 8; ++nb) {
            for (int r = 0; r < 4; ++r) {
                int row = qb0 + wid * 16 + g * 4 + r;
                int col = nb * 16 + l15;
                float y = oacc[nb][r] / lsum[r];
                float gt = b2f(qkv[(size_t)row * 5120 + head * 256 + 128 + col]);
                float sg = 1.f / (1.f + __expf(-gt));
                yg[(size_t)row * 2048 + head * 128 + col] = f2b(y * sg);
            }
        }
    }
}

// ---------------- launch ----------------
extern "C" void kernel_launch(void* const* d_in, const int* in_sizes, int n_in,
                              void* d_out, int out_size, void* d_ws, size_t ws_size,
                              hipStream_t stream) {
    const float* x   = (const float*)d_in[0];
    const int*   pos = (const int*)d_in[1];
    const float* wq  = (const float*)d_in[2];
    const float* wk  = (const float*)d_in[3];
    const float* wv  = (const float*)d_in[4];
    const float* wo  = (const float*)d_in[5];
    const float* qnw = (const float*)d_in[6];
    const float* knw = (const float*)d_in[7];
    float* out = (float*)d_out;
    char* ws = (char*)d_ws;

    // workspace (peak 56 MB):
    u16* wqkvT = (u16*)(ws + 0);           // 5120x2048 bf16 (21.0 MB), freed after qkv GEMM
    u16* woT   = (u16*)(ws + 20971520);    // 2048x2048 bf16 (8.4 MB)
    u16* xb    = (u16*)(ws + 29360128);    // 2048x2048 bf16 (8.4 MB)
    u16* qkv   = (u16*)(ws + 37748736);    // 2048x5120 bf16 (21.0 MB)
    u16* vTb   = (u16*)(ws + 0);           // 4x128x2048 bf16 (2.1 MB), reuses wqkvT region
    u16* ygb   = (u16*)(ws + 4194304);     // 2048x2048 bf16 (8.4 MB), reuses wqkvT region

    k_wtrans<<<dim3(64, 32), 256, 0, stream>>>(wq, wqkvT, 2048, 4096);
    k_wtrans<<<dim3(8, 32), 256, 0, stream>>>(wk, wqkvT + (size_t)4096 * 2048, 2048, 512);
    k_wtrans<<<dim3(8, 32), 256, 0, stream>>>(wv, wqkvT + (size_t)4608 * 2048, 2048, 512);
    k_wtrans<<<dim3(32, 32), 256, 0, stream>>>(wo, woT, 2048, 2048);
    k_xcvt<<<1024, 256, 0, stream>>>(x, xb, 2048 * 2048 / 4);

    k_gemm_bt<false><<<dim3(40, 16), 256, 0, stream>>>(xb, wqkvT, qkv, 2048, 5120, 2048);

    k_normrope<<<2048, 256, 0, stream>>>(qkv, qnw, knw, pos);
    k_vtrans<<<dim3(32, 4), 256, 0, stream>>>(qkv, vTb);

    k_attn<<<dim3(16, 16), 256, 0, stream>>>(qkv, vTb, ygb);

    k_gemm_bt<true><<<dim3(16, 16), 256, 0, stream>>>(ygb, woT, out, 2048, 2048, 2048);
}

// Round 7
// 228.479 us; speedup vs baseline: 2.5727x; 1.2590x over previous
//
#include <hip/hip_runtime.h>
#include <cstdint>
#include <cmath>

using u16 = unsigned short;
typedef __attribute__((ext_vector_type(4))) short s16x4;
typedef __attribute__((ext_vector_type(8))) short s16x8;
typedef __attribute__((ext_vector_type(8))) __bf16 bf16x8;
typedef __attribute__((ext_vector_type(4))) float f32x4;

static __device__ __forceinline__ float b2f(u16 u) {
    unsigned int x = ((unsigned int)u) << 16;
    float f; __builtin_memcpy(&f, &x, 4); return f;
}
static __device__ __forceinline__ u16 f2b(float f) {
    unsigned int x; __builtin_memcpy(&x, &f, 4);
    x += 0x7FFFu + ((x >> 16) & 1u);           // round-to-nearest-even
    return (u16)(x >> 16);
}
static __device__ __forceinline__ bf16x8 as_bf(s16x8 s) {
    return __builtin_bit_cast(bf16x8, s);
}

// ---- async 16B/lane global->LDS (wave-uniform LDS base, per-lane global src) ----
static __device__ __forceinline__ void stage16(const u16* g, u16* lds_base, int lane) {
#if __has_builtin(__builtin_amdgcn_global_load_lds)
    __builtin_amdgcn_global_load_lds((const __attribute__((address_space(1))) void*)g,
                                     (__attribute__((address_space(3))) void*)lds_base,
                                     16, 0, 0);
#else
    *(s16x8*)(lds_base + (size_t)lane * 8) = *(const s16x8*)g;
#endif
}

// ---------------- weight transpose+cvt: in fp32 [K][N] -> out bf16 [N][K] ----------------
__global__ __launch_bounds__(256) void k_wtrans(const float* __restrict__ in,
                                                u16* __restrict__ out,
                                                int K, int N) {
    __shared__ u16 tile[64][72];
    int nb = blockIdx.x * 64, kb = blockIdx.y * 64;
    int tid = threadIdx.x;
    int kr = tid >> 2, c0 = (tid & 3) * 16;
#pragma unroll
    for (int i = 0; i < 4; ++i) {
        f32x4 v = *(const f32x4*)(in + (size_t)(kb + kr) * N + nb + c0 + i * 4);
        s16x4 b;
        for (int j = 0; j < 4; ++j) b[j] = (short)f2b(v[j]);
        *(s16x4*)&tile[kr][c0 + i * 4] = b;
    }
    __syncthreads();
    int nr = tid >> 2, k0 = (tid & 3) * 16;
    s16x8 v0, v1;
    for (int j = 0; j < 8; ++j) { v0[j] = (short)tile[k0 + j][nr]; v1[j] = (short)tile[k0 + 8 + j][nr]; }
    *(s16x8*)(out + (size_t)(nb + nr) * K + kb + k0) = v0;
    *(s16x8*)(out + (size_t)(nb + nr) * K + kb + k0 + 8) = v1;
}

// ---------------- x fp32 -> bf16 ----------------
__global__ __launch_bounds__(256) void k_xcvt(const float* __restrict__ in,
                                              u16* __restrict__ out, int n4) {
    int i = blockIdx.x * 256 + threadIdx.x;
    int stride = gridDim.x * 256;
    for (; i < n4; i += stride) {
        f32x4 v = ((const f32x4*)in)[i];
        s16x4 b;
        for (int j = 0; j < 4; ++j) b[j] = (short)f2b(v[j]);
        ((s16x4*)out)[i] = b;
    }
}

// ------------- GEMM: C[M][N] = A[M][K] @ Bt[N][K]^T  (bf16 in, fp32 acc) -------------
// 128x128 tile, BK=64, 4 waves (2x2), global_load_lds staging, linear LDS.
template <bool OUT_F32>
__global__ __launch_bounds__(256) void k_gemm_bt(const u16* __restrict__ A,
                                                 const u16* __restrict__ Bt,
                                                 void* __restrict__ Cv,
                                                 int M, int N, int K) {
    __shared__ u16 As[128 * 64];
    __shared__ u16 Bs[128 * 64];
    int bm = blockIdx.y * 128, bn = blockIdx.x * 128;
    int tid = threadIdx.x, wid = tid >> 6, lane = tid & 63;
    int l15 = lane & 15, g = lane >> 4;
    int wr = (wid >> 1) * 64, wc = (wid & 1) * 64;
    f32x4 acc[4][4];
    for (int i = 0; i < 4; ++i) for (int j = 0; j < 4; ++j) acc[i][j] = f32x4{0.f, 0.f, 0.f, 0.f};

    int srow = lane >> 3, skcol = (lane & 7) * 8;
    const u16* pa = A + (size_t)(bm + srow) * K + skcol;
    const u16* pb = Bt + (size_t)(bn + srow) * K + skcol;

    for (int kb = 0; kb < K; kb += 64) {
        __syncthreads();
#pragma unroll
        for (int it = 0; it < 4; ++it) {
            int c = it * 4 + wid;
            stage16(pa + (size_t)(c * 8) * K + kb, &As[c * 512], lane);
            stage16(pb + (size_t)(c * 8) * K + kb, &Bs[c * 512], lane);
        }
        __syncthreads();
#pragma unroll
        for (int kk = 0; kk < 64; kk += 32) {
            bf16x8 af[4], bfr[4];
            for (int mi = 0; mi < 4; ++mi)
                af[mi] = as_bf(*(const s16x8*)&As[(wr + mi * 16 + l15) * 64 + kk + g * 8]);
            for (int ni = 0; ni < 4; ++ni)
                bfr[ni] = as_bf(*(const s16x8*)&Bs[(wc + ni * 16 + l15) * 64 + kk + g * 8]);
            for (int mi = 0; mi < 4; ++mi)
                for (int ni = 0; ni < 4; ++ni)
                    acc[mi][ni] = __builtin_amdgcn_mfma_f32_16x16x32_bf16(af[mi], bfr[ni], acc[mi][ni], 0, 0, 0);
        }
    }
    for (int mi = 0; mi < 4; ++mi)
        for (int ni = 0; ni < 4; ++ni) {
            int row = bm + wr + mi * 16 + g * 4;
            int col = bn + wc + ni * 16 + l15;
            for (int rr = 0; rr < 4; ++rr) {
                if (OUT_F32)
                    ((float*)Cv)[(size_t)(row + rr) * N + col] = acc[mi][ni][rr];
                else
                    ((u16*)Cv)[(size_t)(row + rr) * N + col] = f2b(acc[mi][ni][rr]);
            }
        }
}

// ---------------- RMSNorm + RoPE, IN PLACE on fused qkv [2048][5120] ----------------
__global__ __launch_bounds__(256) void k_normrope(u16* __restrict__ qkv,
                                                  const float* __restrict__ qw,
                                                  const float* __restrict__ kw,
                                                  const int* __restrict__ pos) {
    int t = blockIdx.x;
    int tid = threadIdx.x, w = tid >> 6, l = tid & 63;
    float fp = (float)pos[t];
    int j = l & 31;
    float invf = __expf(-(float)j * (9.210340371976184f / 32.f));   // 10000^(-j/32)
    float sv, cv;
    sincosf(fp * invf, &sv, &cv);
    for (int task = w; task < 20; task += 4) {
        u16* p; const float* ww;
        if (task < 16) { p = qkv + (size_t)t * 5120 + task * 256; ww = qw; }
        else           { p = qkv + (size_t)t * 5120 + 4096 + (task - 16) * 128; ww = kw; }
        float v0 = b2f(p[l]), v1 = b2f(p[l + 64]);
        float ss = v0 * v0 + v1 * v1;
        for (int m = 32; m; m >>= 1) ss += __shfl_xor(ss, m);
        float rn = rsqrtf(ss * (1.f / 128.f) + 1e-6f);
        float q0 = v0 * rn * (1.f + ww[l]);
        float q1 = v1 * rn * (1.f + ww[l + 64]);
        float other = __shfl_xor(q0, 32);
        float ro = (l < 32) ? (q0 * cv - other * sv) : (q0 * cv + other * sv);
        p[l] = f2b(ro);
        p[l + 64] = f2b(q1);
    }
}

// ---------------- V transpose: qkv v-cols -> vT[kvh][d 128][t 2048] ----------------
__global__ __launch_bounds__(256) void k_vtrans(const u16* __restrict__ qkv,
                                                u16* __restrict__ vT) {
    __shared__ u16 tile[64][136];
    int tb = blockIdx.x * 64, kvh = blockIdx.y;
    int tid = threadIdx.x;
    int tr = tid >> 2, c0 = (tid & 3) * 32;
    const u16* src = qkv + (size_t)(tb + tr) * 5120 + 4608 + kvh * 128 + c0;
#pragma unroll
    for (int i = 0; i < 4; ++i)
        *(s16x8*)&tile[tr][c0 + i * 8] = *(const s16x8*)(src + i * 8);
    __syncthreads();
    int d = tid >> 1, t0 = (tid & 1) * 32;
    u16* dst = vT + ((size_t)kvh * 128 + d) * 2048 + tb + t0;
#pragma unroll
    for (int i = 0; i < 4; ++i) {
        s16x8 v;
        for (int j = 0; j < 8; ++j) v[j] = (short)tile[t0 + i * 8 + j][d];
        *(s16x8*)(dst + i * 8) = v;
    }
}

// ---------------- causal GQA flash attention, SPLIT-K with static-max softmax ----------------
// block (x = p*2+hf, y = head): processes q-tiles p and 31-p, kv-half hf of each.
// Writes partial O (bf16) and partial row-sum l (fp32); k_combine finishes.
__global__ __launch_bounds__(256) void k_attn_split(const u16* __restrict__ qkv,
                                                    const u16* __restrict__ vT,
                                                    u16* __restrict__ po,
                                                    float* __restrict__ pl) {
    __shared__ u16 Kl[64 * 128];       // XOR-swizzled rows of 256B (gll, pre-swizzled src)
    __shared__ u16 Vt[128][72];        // [d][key], padded
    __shared__ u16 Pl[4][16][72];      // per-wave P tile [qrow][key]
    int head = blockIdx.y, kvh = head >> 2;
    int p = blockIdx.x >> 1, hf = blockIdx.x & 1;
    int tid = threadIdx.x, wid = tid >> 6, lane = tid & 63;
    int l15 = lane & 15, g = lane >> 4;

    for (int sub = 0; sub < 2; ++sub) {
        int qt = sub ? (31 - p) : p;
        int qb0 = qt * 64;
        int nk_all = qt + 1;
        int split = (nk_all + 1) >> 1;
        int ktb = hf ? split : 0;
        int kte = hf ? nk_all : split;

        bf16x8 qf[4];
        {
            const u16* qp = qkv + (size_t)(qb0 + wid * 16 + l15) * 5120 + head * 256 + g * 8;
            for (int c = 0; c < 4; ++c) qf[c] = as_bf(*(const s16x8*)(qp + c * 32));
        }
        f32x4 oacc[8];
        for (int nb = 0; nb < 8; ++nb) oacc[nb] = f32x4{0.f, 0.f, 0.f, 0.f};
        float lsum[4] = {0.f, 0.f, 0.f, 0.f};

        for (int kt = ktb; kt < kte; ++kt) {
            int k0 = kt * 64;
            __syncthreads();
            {   // K: async global->LDS, swizzle baked into the GLOBAL source address
#pragma unroll
                for (int i = 0; i < 4; ++i) {
                    int c = (wid << 2) | i;                 // chunk = 4 rows of 256B
                    int srow = (c << 2) + (lane >> 4);
                    int bofs = (((lane & 15) << 4) ^ ((srow & 7) << 4));
                    const u16* gs = (const u16*)((const char*)(qkv + (size_t)(k0 + srow) * 5120
                                                               + 4096 + kvh * 128) + bofs);
                    stage16(gs, &Kl[c * 512], lane);
                }
                // V: vector loads from pre-transposed vT into padded Vt
                int vr = tid >> 1, vc0 = (tid & 1) * 32;
                const u16* vs = vT + ((size_t)kvh * 128 + vr) * 2048 + k0 + vc0;
#pragma unroll
                for (int c = 0; c < 4; ++c)
                    *(s16x8*)&Vt[vr][vc0 + 8 * c] = *(const s16x8*)(vs + 8 * c);
            }
            __syncthreads();

            f32x4 sc4[4];
            for (int h2 = 0; h2 < 4; ++h2) sc4[h2] = f32x4{0.f, 0.f, 0.f, 0.f};
            for (int h2 = 0; h2 < 4; ++h2) {
                int krow = h2 * 16 + l15;
                const char* kb_ = (const char*)Kl + krow * 256;
                int sw = (krow & 7) << 4;
                for (int c = 0; c < 4; ++c) {
                    bf16x8 kf = as_bf(*(const s16x8*)(kb_ + ((c * 64 + g * 16) ^ sw)));
                    sc4[h2] = __builtin_amdgcn_mfma_f32_16x16x32_bf16(qf[c], kf, sc4[h2], 0, 0, 0);
                }
            }
            // static-max softmax: scores bounded by sqrt(128) ~ 11.32, exp <= 8.2e4
            const float scale = 0.08838834764831845f;   // 1/sqrt(128)
            for (int r = 0; r < 4; ++r) {
                int tq = qb0 + wid * 16 + g * 4 + r;
                float prs = 0.f;
                for (int h2 = 0; h2 < 4; ++h2) {
                    bool msk = (k0 + h2 * 16 + l15) > tq;
                    float pv = msk ? 0.f : __expf(sc4[h2][r] * scale);
                    prs += pv;
                    Pl[wid][g * 4 + r][h2 * 16 + l15] = f2b(pv);
                }
                lsum[r] += prs;     // lane-local; cross-lane reduce deferred to epilogue
            }
            for (int kc = 0; kc < 2; ++kc) {
                bf16x8 pa = as_bf(*(const s16x8*)&Pl[wid][l15][kc * 32 + g * 8]);
                for (int nb = 0; nb < 8; ++nb) {
                    bf16x8 vb = as_bf(*(const s16x8*)&Vt[nb * 16 + l15][kc * 32 + g * 8]);
                    oacc[nb] = __builtin_amdgcn_mfma_f32_16x16x32_bf16(pa, vb, oacc[nb], 0, 0, 0);
                }
            }
        }
        // epilogue: deferred l reduce + partial writes
        u16* pob = po + (((size_t)hf * 16 + head) * 2048) * 128;
        float* plb = pl + ((size_t)hf * 16 + head) * 2048;
        for (int r = 0; r < 4; ++r) {
            float s = lsum[r];
            s += __shfl_xor(s, 1, 16); s += __shfl_xor(s, 2, 16);
            s += __shfl_xor(s, 4, 16); s += __shfl_xor(s, 8, 16);
            int row = qb0 + wid * 16 + g * 4 + r;
            if (l15 == 0) plb[row] = s;
            for (int nb = 0; nb < 8; ++nb)
                pob[(size_t)row * 128 + nb * 16 + l15] = f2b(oacc[nb][r]);
        }
    }
}

// ---------------- combine partials + sigmoid gate -> yg bf16 [2048][2048] ----------------
__global__ __launch_bounds__(256) void k_combine(const u16* __restrict__ po,
                                                 const float* __restrict__ pl,
                                                 const u16* __restrict__ qkv,
                                                 u16* __restrict__ yg) {
    int t = blockIdx.x;
    int tid = threadIdx.x;
    int h = tid >> 4, d0 = (tid & 15) * 8;
    const size_t base = ((size_t)h * 2048 + t) * 128 + d0;
    const size_t hofs = (size_t)16 * 2048 * 128;
    s16x8 a = *(const s16x8*)(po + base);
    s16x8 b = *(const s16x8*)(po + hofs + base);
    float l = pl[(size_t)h * 2048 + t] + pl[(size_t)16 * 2048 + (size_t)h * 2048 + t];
    float inv = 1.f / l;
    s16x8 o;
    for (int j = 0; j < 8; ++j) {
        float y = (b2f((u16)a[j]) + b2f((u16)b[j])) * inv;
        float gt = b2f(qkv[(size_t)t * 5120 + h * 256 + 128 + d0 + j]);
        o[j] = (short)f2b(y / (1.f + __expf(-gt)));
    }
    *(s16x8*)(yg + (size_t)t * 2048 + h * 128 + d0) = o;
}

// ---------------- launch ----------------
extern "C" void kernel_launch(void* const* d_in, const int* in_sizes, int n_in,
                              void* d_out, int out_size, void* d_ws, size_t ws_size,
                              hipStream_t stream) {
    const float* x   = (const float*)d_in[0];
    const int*   pos = (const int*)d_in[1];
    const float* wq  = (const float*)d_in[2];
    const float* wk  = (const float*)d_in[3];
    const float* wv  = (const float*)d_in[4];
    const float* wo  = (const float*)d_in[5];
    const float* qnw = (const float*)d_in[6];
    const float* knw = (const float*)d_in[7];
    float* out = (float*)d_out;
    char* ws = (char*)d_ws;

    // workspace layout (peak 58.7 MB, phase-overlapped):
    u16*   qkv   = (u16*)(ws + 0);          // 2048x5120 bf16 (21.0 MB)         [phase2+]
    u16*   woT   = (u16*)(ws + 20971520);   // 2048x2048 bf16 (8.4 MB)          [all]
    u16*   wqkvT = (u16*)(ws + 29360128);   // 5120x2048 bf16 (21.0 MB)         [phase1-2]
    u16*   xb    = (u16*)(ws + 50331648);   // 2048x2048 bf16 (8.4 MB)          [phase1-2]
    u16*   vTb   = (u16*)(ws + 29360128);   // 4x128x2048 bf16 (2.1 MB)         [phase3+]
    float* plb   = (float*)(ws + 31457280); // 2x16x2048 fp32 (256 KB)          [phase4+]
    u16*   pob   = (u16*)(ws + 31719424);   // 2x16x2048x128 bf16 (16.8 MB)     [phase4+]
    u16*   ygb   = (u16*)(ws + 48496640);   // 2048x2048 bf16 (8.4 MB)          [phase5+]

    k_wtrans<<<dim3(64, 32), 256, 0, stream>>>(wq, wqkvT, 2048, 4096);
    k_wtrans<<<dim3(8, 32), 256, 0, stream>>>(wk, wqkvT + (size_t)4096 * 2048, 2048, 512);
    k_wtrans<<<dim3(8, 32), 256, 0, stream>>>(wv, wqkvT + (size_t)4608 * 2048, 2048, 512);
    k_wtrans<<<dim3(32, 32), 256, 0, stream>>>(wo, woT, 2048, 2048);
    k_xcvt<<<1024, 256, 0, stream>>>(x, xb, 2048 * 2048 / 4);

    k_gemm_bt<false><<<dim3(40, 16), 256, 0, stream>>>(xb, wqkvT, qkv, 2048, 5120, 2048);

    k_normrope<<<2048, 256, 0, stream>>>(qkv, qnw, knw, pos);
    k_vtrans<<<dim3(32, 4), 256, 0, stream>>>(qkv, vTb);

    k_attn_split<<<dim3(32, 16), 256, 0, stream>>>(qkv, vTb, pob, plb);
    k_combine<<<2048, 256, 0, stream>>>(pob, plb, qkv, ygb);

    k_gemm_bt<true><<<dim3(16, 16), 256, 0, stream>>>(ygb, woT, out, 2048, 2048, 2048);
}

// Round 8
// 190.497 us; speedup vs baseline: 3.0857x; 1.1994x over previous
//
#include <hip/hip_runtime.h>
#include <cstdint>
#include <cmath>

using u16 = unsigned short;
typedef __attribute__((ext_vector_type(4))) short s16x4;
typedef __attribute__((ext_vector_type(8))) short s16x8;
typedef __attribute__((ext_vector_type(8))) __bf16 bf16x8;
typedef __attribute__((ext_vector_type(4))) float f32x4;

static __device__ __forceinline__ float b2f(u16 u) {
    unsigned int x = ((unsigned int)u) << 16;
    float f; __builtin_memcpy(&f, &x, 4); return f;
}
static __device__ __forceinline__ u16 f2b(float f) {
    unsigned int x; __builtin_memcpy(&x, &f, 4);
    x += 0x7FFFu + ((x >> 16) & 1u);           // round-to-nearest-even
    return (u16)(x >> 16);
}
static __device__ __forceinline__ bf16x8 as_bf(s16x8 s) {
    return __builtin_bit_cast(bf16x8, s);
}

// ---- async 16B/lane global->LDS (wave-uniform LDS base, per-lane global src) ----
static __device__ __forceinline__ void stage16(const u16* g, u16* lds_base, int lane) {
#if __has_builtin(__builtin_amdgcn_global_load_lds)
    __builtin_amdgcn_global_load_lds((const __attribute__((address_space(1))) void*)g,
                                     (__attribute__((address_space(3))) void*)lds_base,
                                     16, 0, 0);
#else
    *(s16x8*)(lds_base + (size_t)lane * 8) = *(const s16x8*)g;
#endif
}

// ---------------- weight transpose+cvt: in fp32 [K][N] -> out bf16 [N][K] ----------------
__global__ __launch_bounds__(256) void k_wtrans(const float* __restrict__ in,
                                                u16* __restrict__ out,
                                                int K, int N) {
    __shared__ u16 tile[64][72];
    int nb = blockIdx.x * 64, kb = blockIdx.y * 64;
    int tid = threadIdx.x;
    int kr = tid >> 2, c0 = (tid & 3) * 16;
#pragma unroll
    for (int i = 0; i < 4; ++i) {
        f32x4 v = *(const f32x4*)(in + (size_t)(kb + kr) * N + nb + c0 + i * 4);
        s16x4 b;
        for (int j = 0; j < 4; ++j) b[j] = (short)f2b(v[j]);
        *(s16x4*)&tile[kr][c0 + i * 4] = b;
    }
    __syncthreads();
    int nr = tid >> 2, k0 = (tid & 3) * 16;
    s16x8 v0, v1;
    for (int j = 0; j < 8; ++j) { v0[j] = (short)tile[k0 + j][nr]; v1[j] = (short)tile[k0 + 8 + j][nr]; }
    *(s16x8*)(out + (size_t)(nb + nr) * K + kb + k0) = v0;
    *(s16x8*)(out + (size_t)(nb + nr) * K + kb + k0 + 8) = v1;
}

// ---------------- x fp32 -> bf16 ----------------
__global__ __launch_bounds__(256) void k_xcvt(const float* __restrict__ in,
                                              u16* __restrict__ out, int n4) {
    int i = blockIdx.x * 256 + threadIdx.x;
    int stride = gridDim.x * 256;
    for (; i < n4; i += stride) {
        f32x4 v = ((const f32x4*)in)[i];
        s16x4 b;
        for (int j = 0; j < 4; ++j) b[j] = (short)f2b(v[j]);
        ((s16x4*)out)[i] = b;
    }
}

// ------------- GEMM: C[M][N] = A[M][K] @ Bt[N][K]^T  (bf16 in, fp32 acc) -------------
// 128x128 tile, BK=64, 4 waves (2x2), global_load_lds staging with source-baked
// XOR swizzle (LDS rows 128B; read applies same XOR) + XCD-aware block remap.
template <bool OUT_F32>
__global__ __launch_bounds__(256) void k_gemm_bt(const u16* __restrict__ A,
                                                 const u16* __restrict__ Bt,
                                                 void* __restrict__ Cv,
                                                 int M, int N, int K) {
    __shared__ u16 As[128 * 64];
    __shared__ u16 Bs[128 * 64];
    // XCD-aware bijective remap (m204): consecutive wgid within an XCD
    int nx = gridDim.x, nwg = nx * gridDim.y;
    int flat = blockIdx.y * nx + blockIdx.x;
    int q = nwg >> 3, r = nwg & 7;
    int xcd = flat & 7, idx = flat >> 3;
    int wgid = (xcd < r ? xcd * (q + 1) : r * (q + 1) + (xcd - r) * q) + idx;
    int bn = (wgid % nx) * 128, bm = (wgid / nx) * 128;

    int tid = threadIdx.x, wid = tid >> 6, lane = tid & 63;
    int l15 = lane & 15, g = lane >> 4;
    int wr = (wid >> 1) * 64, wc = (wid & 1) * 64;
    f32x4 acc[4][4];
    for (int i = 0; i < 4; ++i) for (int j = 0; j < 4; ++j) acc[i][j] = f32x4{0.f, 0.f, 0.f, 0.f};

    // staging: chunk c = 8 rows x 64 u16 (512 u16 linear LDS). lane -> row c*8+(lane>>3),
    // source col = swizzled involution so that LDS[r][s] holds global col s^((r&7)<<4).
    int srow = lane >> 3;
    int scol = ((lane & 7) * 8) ^ (srow << 3);           // u16 units, = byte ((lane&7)*16)^((r&7)<<4)
    const u16* pa = A + (size_t)(bm + srow) * K + scol;
    const u16* pb = Bt + (size_t)(bn + srow) * K + scol;

    for (int kb = 0; kb < K; kb += 64) {
        __syncthreads();
#pragma unroll
        for (int it = 0; it < 4; ++it) {
            int c = it * 4 + wid;
            stage16(pa + (size_t)(c * 8) * K + kb, &As[c * 512], lane);
            stage16(pb + (size_t)(c * 8) * K + kb, &Bs[c * 512], lane);
        }
        __syncthreads();
        int swz = (l15 & 7) << 4;                        // row&7 == l15&7 (16-aligned wr/mi)
#pragma unroll
        for (int kk = 0; kk < 64; kk += 32) {
            bf16x8 af[4], bfr[4];
            for (int mi = 0; mi < 4; ++mi) {
                const char* rp = (const char*)As + (wr + mi * 16 + l15) * 128;
                af[mi] = as_bf(*(const s16x8*)(rp + ((kk * 2 + g * 16) ^ swz)));
            }
            for (int ni = 0; ni < 4; ++ni) {
                const char* rp = (const char*)Bs + (wc + ni * 16 + l15) * 128;
                bfr[ni] = as_bf(*(const s16x8*)(rp + ((kk * 2 + g * 16) ^ swz)));
            }
            for (int mi = 0; mi < 4; ++mi)
                for (int ni = 0; ni < 4; ++ni)
                    acc[mi][ni] = __builtin_amdgcn_mfma_f32_16x16x32_bf16(af[mi], bfr[ni], acc[mi][ni], 0, 0, 0);
        }
    }
    for (int mi = 0; mi < 4; ++mi)
        for (int ni = 0; ni < 4; ++ni) {
            int row = bm + wr + mi * 16 + g * 4;
            int col = bn + wc + ni * 16 + l15;
            for (int rr = 0; rr < 4; ++rr) {
                if (OUT_F32)
                    ((float*)Cv)[(size_t)(row + rr) * N + col] = acc[mi][ni][rr];
                else
                    ((u16*)Cv)[(size_t)(row + rr) * N + col] = f2b(acc[mi][ni][rr]);
            }
        }
}

// ---------------- RMSNorm + RoPE, IN PLACE on fused qkv [2048][5120] ----------------
__global__ __launch_bounds__(256) void k_normrope(u16* __restrict__ qkv,
                                                  const float* __restrict__ qw,
                                                  const float* __restrict__ kw,
                                                  const int* __restrict__ pos) {
    int t = blockIdx.x;
    int tid = threadIdx.x, w = tid >> 6, l = tid & 63;
    float fp = (float)pos[t];
    int j = l & 31;
    float invf = __expf(-(float)j * (9.210340371976184f / 32.f));   // 10000^(-j/32)
    float sv, cv;
    sincosf(fp * invf, &sv, &cv);
    for (int task = w; task < 20; task += 4) {
        u16* p; const float* ww;
        if (task < 16) { p = qkv + (size_t)t * 5120 + task * 256; ww = qw; }
        else           { p = qkv + (size_t)t * 5120 + 4096 + (task - 16) * 128; ww = kw; }
        float v0 = b2f(p[l]), v1 = b2f(p[l + 64]);
        float ss = v0 * v0 + v1 * v1;
        for (int m = 32; m; m >>= 1) ss += __shfl_xor(ss, m);
        float rn = rsqrtf(ss * (1.f / 128.f) + 1e-6f);
        float q0 = v0 * rn * (1.f + ww[l]);
        float q1 = v1 * rn * (1.f + ww[l + 64]);
        float other = __shfl_xor(q0, 32);
        float ro = (l < 32) ? (q0 * cv - other * sv) : (q0 * cv + other * sv);
        p[l] = f2b(ro);
        p[l + 64] = f2b(q1);
    }
}

// ---------------- V transpose: qkv v-cols -> vT[kvh][d 128][t 2048] ----------------
__global__ __launch_bounds__(256) void k_vtrans(const u16* __restrict__ qkv,
                                                u16* __restrict__ vT) {
    __shared__ u16 tile[64][136];
    int tb = blockIdx.x * 64, kvh = blockIdx.y;
    int tid = threadIdx.x;
    int tr = tid >> 2, c0 = (tid & 3) * 32;
    const u16* src = qkv + (size_t)(tb + tr) * 5120 + 4608 + kvh * 128 + c0;
#pragma unroll
    for (int i = 0; i < 4; ++i)
        *(s16x8*)&tile[tr][c0 + i * 8] = *(const s16x8*)(src + i * 8);
    __syncthreads();
    int d = tid >> 1, t0 = (tid & 1) * 32;
    u16* dst = vT + ((size_t)kvh * 128 + d) * 2048 + tb + t0;
#pragma unroll
    for (int i = 0; i < 4; ++i) {
        s16x8 v;
        for (int j = 0; j < 8; ++j) v[j] = (short)tile[t0 + i * 8 + j][d];
        *(s16x8*)(dst + i * 8) = v;
    }
}

// ---------------- causal GQA flash attention, SPLIT-K with static-max softmax ----------------
__global__ __launch_bounds__(256) void k_attn_split(const u16* __restrict__ qkv,
                                                    const u16* __restrict__ vT,
                                                    u16* __restrict__ po,
                                                    float* __restrict__ pl) {
    __shared__ u16 Kl[64 * 128];       // XOR-swizzled rows of 256B (gll, pre-swizzled src)
    __shared__ u16 Vt[128][72];        // [d][key], padded
    __shared__ u16 Pl[4][16][72];      // per-wave P tile [qrow][key]
    int head = blockIdx.y, kvh = head >> 2;
    int p = blockIdx.x >> 1, hf = blockIdx.x & 1;
    int tid = threadIdx.x, wid = tid >> 6, lane = tid & 63;
    int l15 = lane & 15, g = lane >> 4;

    for (int sub = 0; sub < 2; ++sub) {
        int qt = sub ? (31 - p) : p;
        int qb0 = qt * 64;
        int nk_all = qt + 1;
        int split = (nk_all + 1) >> 1;
        int ktb = hf ? split : 0;
        int kte = hf ? nk_all : split;

        bf16x8 qf[4];
        {
            const u16* qp = qkv + (size_t)(qb0 + wid * 16 + l15) * 5120 + head * 256 + g * 8;
            for (int c = 0; c < 4; ++c) qf[c] = as_bf(*(const s16x8*)(qp + c * 32));
        }
        f32x4 oacc[8];
        for (int nb = 0; nb < 8; ++nb) oacc[nb] = f32x4{0.f, 0.f, 0.f, 0.f};
        float lsum[4] = {0.f, 0.f, 0.f, 0.f};

        for (int kt = ktb; kt < kte; ++kt) {
            int k0 = kt * 64;
            __syncthreads();
            {   // K: async global->LDS, swizzle baked into the GLOBAL source address
#pragma unroll
                for (int i = 0; i < 4; ++i) {
                    int c = (wid << 2) | i;                 // chunk = 4 rows of 256B
                    int srow = (c << 2) + (lane >> 4);
                    int bofs = (((lane & 15) << 4) ^ ((srow & 7) << 4));
                    const u16* gs = (const u16*)((const char*)(qkv + (size_t)(k0 + srow) * 5120
                                                               + 4096 + kvh * 128) + bofs);
                    stage16(gs, &Kl[c * 512], lane);
                }
                // V: vector loads from pre-transposed vT into padded Vt
                int vr = tid >> 1, vc0 = (tid & 1) * 32;
                const u16* vs = vT + ((size_t)kvh * 128 + vr) * 2048 + k0 + vc0;
#pragma unroll
                for (int c = 0; c < 4; ++c)
                    *(s16x8*)&Vt[vr][vc0 + 8 * c] = *(const s16x8*)(vs + 8 * c);
            }
            __syncthreads();

            f32x4 sc4[4];
            for (int h2 = 0; h2 < 4; ++h2) sc4[h2] = f32x4{0.f, 0.f, 0.f, 0.f};
            for (int h2 = 0; h2 < 4; ++h2) {
                int krow = h2 * 16 + l15;
                const char* kb_ = (const char*)Kl + krow * 256;
                int sw = (krow & 7) << 4;
                for (int c = 0; c < 4; ++c) {
                    bf16x8 kf = as_bf(*(const s16x8*)(kb_ + ((c * 64 + g * 16) ^ sw)));
                    sc4[h2] = __builtin_amdgcn_mfma_f32_16x16x32_bf16(qf[c], kf, sc4[h2], 0, 0, 0);
                }
            }
            // static-max softmax: scores bounded by sqrt(128) ~ 11.32, exp <= 8.2e4
            const float scale = 0.08838834764831845f;   // 1/sqrt(128)
            for (int r = 0; r < 4; ++r) {
                int tq = qb0 + wid * 16 + g * 4 + r;
                float prs = 0.f;
                for (int h2 = 0; h2 < 4; ++h2) {
                    bool msk = (k0 + h2 * 16 + l15) > tq;
                    float pv = msk ? 0.f : __expf(sc4[h2][r] * scale);
                    prs += pv;
                    Pl[wid][g * 4 + r][h2 * 16 + l15] = f2b(pv);
                }
                lsum[r] += prs;     // lane-local; cross-lane reduce deferred to epilogue
            }
            for (int kc = 0; kc < 2; ++kc) {
                bf16x8 pa = as_bf(*(const s16x8*)&Pl[wid][l15][kc * 32 + g * 8]);
                for (int nb = 0; nb < 8; ++nb) {
                    bf16x8 vb = as_bf(*(const s16x8*)&Vt[nb * 16 + l15][kc * 32 + g * 8]);
                    oacc[nb] = __builtin_amdgcn_mfma_f32_16x16x32_bf16(pa, vb, oacc[nb], 0, 0, 0);
                }
            }
        }
        // epilogue: deferred l reduce + partial writes
        u16* pob = po + (((size_t)hf * 16 + head) * 2048) * 128;
        float* plb = pl + ((size_t)hf * 16 + head) * 2048;
        for (int r = 0; r < 4; ++r) {
            float s = lsum[r];
            s += __shfl_xor(s, 1, 16); s += __shfl_xor(s, 2, 16);
            s += __shfl_xor(s, 4, 16); s += __shfl_xor(s, 8, 16);
            int row = qb0 + wid * 16 + g * 4 + r;
            if (l15 == 0) plb[row] = s;
            for (int nb = 0; nb < 8; ++nb)
                pob[(size_t)row * 128 + nb * 16 + l15] = f2b(oacc[nb][r]);
        }
    }
}

// ---------------- combine partials + sigmoid gate -> yg bf16 [2048][2048] ----------------
__global__ __launch_bounds__(256) void k_combine(const u16* __restrict__ po,
                                                 const float* __restrict__ pl,
                                                 const u16* __restrict__ qkv,
                                                 u16* __restrict__ yg) {
    int t = blockIdx.x;
    int tid = threadIdx.x;
    int h = tid >> 4, d0 = (tid & 15) * 8;
    const size_t base = ((size_t)h * 2048 + t) * 128 + d0;
    const size_t hofs = (size_t)16 * 2048 * 128;
    s16x8 a = *(const s16x8*)(po + base);
    s16x8 b = *(const s16x8*)(po + hofs + base);
    float l = pl[(size_t)h * 2048 + t] + pl[(size_t)16 * 2048 + (size_t)h * 2048 + t];
    float inv = 1.f / l;
    s16x8 o;
    for (int j = 0; j < 8; ++j) {
        float y = (b2f((u16)a[j]) + b2f((u16)b[j])) * inv;
        float gt = b2f(qkv[(size_t)t * 5120 + h * 256 + 128 + d0 + j]);
        o[j] = (short)f2b(y / (1.f + __expf(-gt)));
    }
    *(s16x8*)(yg + (size_t)t * 2048 + h * 128 + d0) = o;
}

// ---------------- launch ----------------
extern "C" void kernel_launch(void* const* d_in, const int* in_sizes, int n_in,
                              void* d_out, int out_size, void* d_ws, size_t ws_size,
                              hipStream_t stream) {
    const float* x   = (const float*)d_in[0];
    const int*   pos = (const int*)d_in[1];
    const float* wq  = (const float*)d_in[2];
    const float* wk  = (const float*)d_in[3];
    const float* wv  = (const float*)d_in[4];
    const float* wo  = (const float*)d_in[5];
    const float* qnw = (const float*)d_in[6];
    const float* knw = (const float*)d_in[7];
    float* out = (float*)d_out;
    char* ws = (char*)d_ws;

    // workspace layout (peak 58.7 MB, phase-overlapped):
    u16*   qkv   = (u16*)(ws + 0);          // 2048x5120 bf16 (21.0 MB)         [phase2+]
    u16*   woT   = (u16*)(ws + 20971520);   // 2048x2048 bf16 (8.4 MB)          [all]
    u16*   wqkvT = (u16*)(ws + 29360128);   // 5120x2048 bf16 (21.0 MB)         [phase1-2]
    u16*   xb    = (u16*)(ws + 50331648);   // 2048x2048 bf16 (8.4 MB)          [phase1-2]
    u16*   vTb   = (u16*)(ws + 29360128);   // 4x128x2048 bf16 (2.1 MB)         [phase3+]
    float* plb   = (float*)(ws + 31457280); // 2x16x2048 fp32 (256 KB)          [phase4+]
    u16*   pob   = (u16*)(ws + 31719424);   // 2x16x2048x128 bf16 (16.8 MB)     [phase4+]
    u16*   ygb   = (u16*)(ws + 48496640);   // 2048x2048 bf16 (8.4 MB)          [phase5+]

    k_wtrans<<<dim3(64, 32), 256, 0, stream>>>(wq, wqkvT, 2048, 4096);
    k_wtrans<<<dim3(8, 32), 256, 0, stream>>>(wk, wqkvT + (size_t)4096 * 2048, 2048, 512);
    k_wtrans<<<dim3(8, 32), 256, 0, stream>>>(wv, wqkvT + (size_t)4608 * 2048, 2048, 512);
    k_wtrans<<<dim3(32, 32), 256, 0, stream>>>(wo, woT, 2048, 2048);
    k_xcvt<<<1024, 256, 0, stream>>>(x, xb, 2048 * 2048 / 4);

    k_gemm_bt<false><<<dim3(40, 16), 256, 0, stream>>>(xb, wqkvT, qkv, 2048, 5120, 2048);

    k_normrope<<<2048, 256, 0, stream>>>(qkv, qnw, knw, pos);
    k_vtrans<<<dim3(32, 4), 256, 0, stream>>>(qkv, vTb);

    k_attn_split<<<dim3(32, 16), 256, 0, stream>>>(qkv, vTb, pob, plb);
    k_combine<<<2048, 256, 0, stream>>>(pob, plb, qkv, ygb);

    k_gemm_bt<true><<<dim3(16, 16), 256, 0, stream>>>(ygb, woT, out, 2048, 2048, 2048);
}